// Round 22
// baseline (169.671 us; speedup 1.0000x reference)
//
#include <hip/hip_runtime.h>

typedef unsigned int u32;
typedef unsigned long long u64;

#define NPTS   1000000
#define KSTEPS 32
#define NF     8
#define IMG_H  1024
#define IMG_W  1024
#define FID    1000
#define HW     (IMG_H * IMG_W)
#define NB     3907            // ceil(NPTS/256)
#define NBKT   512             // bucket = pixel >> 11  (2 image rows)
#define BKTPX  2048            // pixels per bucket
#define SEGW   (256 * KSTEPS)  // 8192 words per block-major segment
#define K5G    1024            // accumulate grid (>= PARTCH)
#define PARTCH 1016            // max chunks = 512 + 504
#define PARTA_CH 488           // chunk tiles aliased over counts+lpre region
#define MSTG   512             // meta staging span (g's per stage)
#define TT     64              // transpose tile
#define FPSCALE 4194304.0f     // 2^22 fixed point; capacity 1024 > max sum 488
#define FPINV   (1.0f / 4194304.0f)

// Extract step K's function index from packed nibble words p0..p3.
#define GETIDX(K)                                                              \
    ((int)(((((K) >> 3) == 0 ? p0 : ((K) >> 3) == 1 ? p1                       \
            : ((K) >> 3) == 2 ? p2 : p3) >> (((K) & 7) * 4)) & 7u))

// One chaos-game step, numpy-exact (no FMA contraction). Scalar LDS table
// reads: 8 distinct rows max -> broadcast/2-way aliasing (free on CDNA4).
#define FLAME_STEP(IDX, K)                                                     \
  {                                                                            \
    const float a00 = s_tab[(IDX)*8+0], a01 = s_tab[(IDX)*8+1];                \
    const float a10 = s_tab[(IDX)*8+2], a11 = s_tab[(IDX)*8+3];                \
    const float b0  = s_tab[(IDX)*8+4], b1  = s_tab[(IDX)*8+5];                \
    const float fc  = s_tab[(IDX)*8+6];                                        \
    const float nx = __fadd_rn(__fadd_rn(__fmul_rn(a00,x),__fmul_rn(a01,y)),b0);\
    const float ny = __fadd_rn(__fadd_rn(__fmul_rn(a10,x),__fmul_rn(a11,y)),b1);\
    x = nx; y = ny;                                                            \
    c = __fmul_rn(__fadd_rn(c, fc), 0.5f);                                     \
    xb = (int)__fmul_rn(__fsub_rn(x, minx), rx);                               \
    yb = (int)__fmul_rn(__fsub_rn(y, miny), ry);                               \
    inb = (xb >= 0) & (xb < IMG_W) & (yb >= 0) & (yb < IMG_H) & ((K) >= skipk);\
  }

#define LOAD_TABLES()                                                          \
    if (threadIdx.x < NF) {                                                    \
        const int f = threadIdx.x;                                             \
        s_tab[f*8+0] = Amat[f*4+0]; s_tab[f*8+1] = Amat[f*4+1];                \
        s_tab[f*8+2] = Amat[f*4+2]; s_tab[f*8+3] = Amat[f*4+3];                \
        s_tab[f*8+4] = bvec[f*2+0]; s_tab[f*8+5] = bvec[f*2+1];                \
        s_tab[f*8+6] = fcolor[f];   s_tab[f*8+7] = 0.0f;                       \
    }

__device__ __forceinline__ u32* part_ptr(u32* partA, u32* partB, u32 w) {
    return (w < PARTA_CH) ? partA + (size_t)w * (BKTPX * 4)
                          : partB + (size_t)(w - PARTA_CH) * (BKTPX * 4);
}
__device__ __forceinline__ const u32* part_ptr_c(const u32* partA,
                                                 const u32* partB, u32 w) {
    return (w < PARTA_CH) ? partA + (size_t)w * (BKTPX * 4)
                          : partB + (size_t)(w - PARTA_CH) * (BKTPX * 4);
}

// Wave-level inclusive scan of v across the 64-lane wave (6 shfl steps).
__device__ __forceinline__ u32 wave_incl_scan(u32 v, int lane) {
    #pragma unroll
    for (int o = 1; o < 64; o <<= 1) {
        const u32 n = __shfl_up(v, o);
        if (lane >= o) v += n;
    }
    return v;
}

// ---------------------------------------------------------------------------
// K1: the ONLY flame pass. v2: PER-WAVE count/cursor arrays (s_cntw[4][512])
// -> phase-A count atomics and phase-B scatter atomics hit wave-private
// arrays, eliminating inter-wave same-address serialization on hot buckets
// (~4x contention cut). Bucket segments filled wave0..wave3 (integer sums
// commute -> output bit-identical).
// ---------------------------------------------------------------------------
__global__ __launch_bounds__(256) void k_flame(
    const float* __restrict__ Amat, const float* __restrict__ bvec,
    const float* __restrict__ fcolor,
    const float* __restrict__ xy0, const float* __restrict__ c0,
    const float* __restrict__ minv, const float* __restrict__ rangev,
    const int* __restrict__ fn_idx, const int* __restrict__ skipk_ptr,
    u32* __restrict__ counts, u32* __restrict__ lpre,
    u32* __restrict__ blockmajor)
{
    __shared__ u32 s_rec[SEGW];          // 32 KB
    __shared__ u32 s_cntw[4 * NBKT];     // per-wave counts, then cursors (8KB)
    __shared__ u32 s_wsum[4];
    __shared__ u32 s_vt;
    __shared__ float s_tab[NF * 8];
    const int tid = threadIdx.x;
    const int lane = tid & 63, wav = tid >> 6;

    #pragma unroll
    for (int j = 0; j < 8; ++j) s_cntw[tid + 256 * j] = 0u;
    LOAD_TABLES();
    __syncthreads();

    const int i = blockIdx.x * 256 + tid;
    u32 rec[KSTEPS];

    if (i < NPTS) {
        u32 p0 = 0, p1 = 0, p2 = 0, p3 = 0;
        #pragma unroll
        for (int k = 0; k < 8; ++k)
            p0 |= ((u32)fn_idx[(size_t)k * NPTS + i] & 7u) << (k * 4);
        #pragma unroll
        for (int k = 0; k < 8; ++k)
            p1 |= ((u32)fn_idx[(size_t)(k + 8) * NPTS + i] & 7u) << (k * 4);
        #pragma unroll
        for (int k = 0; k < 8; ++k)
            p2 |= ((u32)fn_idx[(size_t)(k + 16) * NPTS + i] & 7u) << (k * 4);
        #pragma unroll
        for (int k = 0; k < 8; ++k)
            p3 |= ((u32)fn_idx[(size_t)(k + 24) * NPTS + i] & 7u) << (k * 4);

        const int   skipk = skipk_ptr[0];
        const float minx = minv[0], miny = minv[1];
        const float rx = rangev[0], ry = rangev[1];
        const float2 xyv = ((const float2*)xy0)[i];
        float x = xyv.x, y = xyv.y, c = c0[i];
        #pragma unroll
        for (int k = 0; k < KSTEPS; ++k) {
            const int idx = GETIDX(k);
            int xb, yb; bool inb;
            FLAME_STEP(idx, k);
            u32 r = 0xFFFFFFFFu;
            if (inb) {
                int pi = (int)__fadd_rn(__fmul_rn(c, 999.0f), 0.0005f);
                pi = min(max(pi, 0), FID - 1);
                r = (((u32)(xb << 10 | yb)) << 10) | (u32)pi;
                atomicAdd(&s_cntw[wav * NBKT + (r >> 21)], 1u);
            }
            rec[k] = r;
        }
    }
    __syncthreads();

    // Per-bucket totals from the 4 wave copies (thread owns buckets 2tid,
    // 2tid+1), then shuffle-based exclusive scan over 512 buckets.
    const int bA = 2 * tid, bB = 2 * tid + 1;
    const u32 c0A = s_cntw[0*NBKT + bA], c1A = s_cntw[1*NBKT + bA];
    const u32 c2A = s_cntw[2*NBKT + bA], c3A = s_cntw[3*NBKT + bA];
    const u32 c0B = s_cntw[0*NBKT + bB], c1B = s_cntw[1*NBKT + bB];
    const u32 c2B = s_cntw[2*NBKT + bB], c3B = s_cntw[3*NBKT + bB];
    const u32 cA = c0A + c1A + c2A + c3A;
    const u32 cB = c0B + c1B + c2B + c3B;
    const u32 psum = cA + cB;
    u32 v = wave_incl_scan(psum, lane);
    if (lane == 63) s_wsum[wav] = v;
    __syncthreads();
    u32 off = 0;
    #pragma unroll
    for (int wv = 0; wv < 4; ++wv)
        if (wv < wav) off += s_wsum[wv];
    const u32 incl = v + off;
    const u32 excl = incl - psum;

    // Per-wave cursors (wave w's records land after waves <w in the bucket
    // segment); per-(block,bucket) meta to global (coalesced).
    u32 cur = excl;
    s_cntw[0*NBKT + bA] = cur; cur += c0A;
    s_cntw[1*NBKT + bA] = cur; cur += c1A;
    s_cntw[2*NBKT + bA] = cur; cur += c2A;
    s_cntw[3*NBKT + bA] = cur;
    u32 cur2 = excl + cA;
    s_cntw[0*NBKT + bB] = cur2; cur2 += c0B;
    s_cntw[1*NBKT + bB] = cur2; cur2 += c1B;
    s_cntw[2*NBKT + bB] = cur2; cur2 += c2B;
    s_cntw[3*NBKT + bB] = cur2;
    const size_t g0 = (size_t)blockIdx.x * NBKT;
    lpre[g0 + bA] = excl;  lpre[g0 + bB] = excl + cA;
    counts[g0 + bA] = cA;  counts[g0 + bB] = cB;
    if (tid == 255) s_vt = incl;         // total valid records
    __syncthreads();

    // Re-scatter rec[] from VGPRs into LDS, bucket-sorted (per-wave cursor).
    if (i < NPTS) {
        #pragma unroll
        for (int k = 0; k < KSTEPS; ++k) {
            const u32 r = rec[k];
            if (r != 0xFFFFFFFFu) {
                const u32 pos = atomicAdd(&s_cntw[wav * NBKT + (r >> 21)], 1u);
                s_rec[pos] = r;
            }
        }
    }
    __syncthreads();

    // Dense copy to block-major segment (uint4).
    const u32 vt = s_vt;
    u32* dst = blockmajor + (size_t)blockIdx.x * SEGW;
    const u32 nv4 = vt >> 2;
    for (u32 q = tid; q < nv4; q += 256)
        ((uint4*)dst)[q] = make_uint4(s_rec[4*q], s_rec[4*q+1],
                                      s_rec[4*q+2], s_rec[4*q+3]);
    for (u32 j = (nv4 << 2) + tid; j < vt; j += 256) dst[j] = s_rec[j];
}

// ---------------------------------------------------------------------------
// K2: LDS-tiled transpose (64x64, +1-pad) — coalesced both sides. Totals via
// per-block partial sums + one atomic wave (totals pre-zeroed).
// ---------------------------------------------------------------------------
__global__ __launch_bounds__(256) void k_transpose(
    const u32* __restrict__ counts, const u32* __restrict__ lpre,
    u32* __restrict__ counts_t, u32* __restrict__ lpre_t,
    u32* __restrict__ totals)
{
    __shared__ u32 tc[TT][TT + 1];
    __shared__ u32 tl[TT][TT + 1];
    __shared__ u32 psum[4][TT];
    const int tx = threadIdx.x & 63, ty = threadIdx.x >> 6;
    const int b0 = blockIdx.x * TT;      // bucket tile (NBKT/TT = 8)
    const int g0 = blockIdx.y * TT;      // block-row tile (ceil(NB/TT) = 62)

    u32 colsum = 0;
    #pragma unroll
    for (int j = 0; j < 16; ++j) {
        const int g = g0 + ty * 16 + j;
        u32 cv = 0, lv = 0;
        if (g < NB) {
            cv = counts[(size_t)g * NBKT + b0 + tx];   // coalesced
            lv = lpre[(size_t)g * NBKT + b0 + tx];     // coalesced
        }
        tc[ty * 16 + j][tx] = cv;
        tl[ty * 16 + j][tx] = lv;
        colsum += cv;
    }
    psum[ty][tx] = colsum;
    __syncthreads();

    if (ty == 0) {
        const u32 s = psum[0][tx] + psum[1][tx] + psum[2][tx] + psum[3][tx];
        if (s) atomicAdd(&totals[b0 + tx], s);
    }

    #pragma unroll
    for (int j = 0; j < 16; ++j) {
        const int b = b0 + ty * 16 + j;
        const int g = g0 + tx;
        if (g < NB) {
            counts_t[(size_t)b * NB + g] = tc[tx][ty * 16 + j];  // coalesced
            lpre_t[(size_t)b * NB + g]   = tl[tx][ty * 16 + j];  // coalesced
        }
    }
}

// ---------------------------------------------------------------------------
// K3: chunk counts m[b], wstart scan, fixed-point palette. 1 wg x 512.
// ---------------------------------------------------------------------------
__global__ __launch_bounds__(512) void k_meta(
    const float* __restrict__ palette,
    const u32* __restrict__ totals,
    u32* __restrict__ mm, u32* __restrict__ wstart,
    u32* __restrict__ pal_u32)
{
    __shared__ u32 sc[NBKT];
    const int tid = threadIdx.x;

    for (int t = tid; t < FID * 4; t += 512)
        pal_u32[t] = __float2uint_rn(__fmul_rn(palette[t], FPSCALE));

    const u32 t0 = totals[tid];
    sc[tid] = t0; __syncthreads();
    #pragma unroll
    for (int o = 1; o < NBKT; o <<= 1) {
        u32 v = (tid >= o) ? sc[tid - o] : 0u;
        __syncthreads(); sc[tid] += v; __syncthreads();
    }
    const u32 total = sc[NBKT - 1];

    const u32 m = 1u + (total ? (u32)((504ull * t0) / total) : 0u);
    mm[tid] = m;
    __syncthreads(); sc[tid] = m; __syncthreads();
    #pragma unroll
    for (int o = 1; o < NBKT; o <<= 1) {
        u32 v = (tid >= o) ? sc[tid - o] : 0u;
        __syncthreads(); sc[tid] += v; __syncthreads();
    }
    wstart[tid] = sc[tid] - m;
    if (tid == NBKT - 1) wstart[NBKT] = sc[NBKT - 1];
}

// ---------------------------------------------------------------------------
// K4 v10: round-16 v6 walk + shuffle scan (byte-identical to round-21).
// ---------------------------------------------------------------------------
__global__ __launch_bounds__(512) void k_accum(
    const u32* __restrict__ pal_u32,
    const u32* __restrict__ counts_t, const u32* __restrict__ lpre_t,
    const u32* __restrict__ mm, const u32* __restrict__ wstart,
    const u32* __restrict__ blockmajor,
    u32* __restrict__ partA, u32* __restrict__ partB)
{
    __shared__ u64 tileA[BKTPX];        // ch0|ch1 (16 KB)
    __shared__ u64 tileB[BKTPX];        // ch2|ch3 (16 KB)
    __shared__ u32 s_ml[MSTG];          // staged lp (2 KB)
    __shared__ u32 s_pfx[MSTG + 1];     // run starts
    __shared__ u32 s_ws[NBKT + 1];
    __shared__ u32 s_wsum[8];
    const int tid = threadIdx.x, w = blockIdx.x;
    const int lane = tid & 63, wav = tid >> 6;

    if (tid < NBKT) s_ws[tid] = wstart[tid];
    if (tid == 0)   s_ws[NBKT] = wstart[NBKT];
    __syncthreads();
    if ((u32)w >= s_ws[NBKT]) return;   // uniform per block

    int b = 0;
    #pragma unroll
    for (int step = 256; step; step >>= 1)
        if (b + step <= NBKT - 1 && s_ws[b + step] <= (u32)w) b += step;

    for (int t = tid; t < BKTPX; t += 512) { tileA[t] = 0ull; tileB[t] = 0ull; }

    const u32 m = mm[b], cch = (u32)w - s_ws[b];
    const u32 gs = (u32)(((u64)NB * cch) / m);
    const u32 ge = (u32)(((u64)NB * (cch + 1)) / m);

    const uint4* pal4 = (const uint4*)pal_u32;
    const u32* ct = counts_t + (size_t)b * NB;
    const u32* lt = lpre_t + (size_t)b * NB;

    for (u32 g0 = gs; g0 < ge; g0 += MSTG) {
        const u32 nm = min((u32)MSTG, ge - g0);
        __syncthreads();                 // protect prior stage's readers
        const u32 myc = (tid < (int)nm) ? ct[g0 + tid] : 0u;   // coalesced
        if (tid < (int)nm) s_ml[tid] = lt[g0 + tid];           // coalesced

        // Shuffle-based inclusive scan of myc over 512 threads (2 barriers).
        u32 v = wave_incl_scan(myc, lane);
        if (lane == 63) s_wsum[wav] = v;
        __syncthreads();
        u32 off = 0;
        #pragma unroll
        for (int wv = 0; wv < 8; ++wv)
            if (wv < wav) off += s_wsum[wv];
        s_pfx[tid + 1] = v + off;        // inclusive
        if (tid == 0) s_pfx[0] = 0u;
        __syncthreads();
        const u32 R = s_pfx[MSTG];       // records in this stage

        // Flat, balanced walk with one-ahead pipeline (v6 structure).
        u32 idx = (u32)tid;
        u32 r_c = 0;
        if (idx < R) {
            u32 g = 0;
            #pragma unroll
            for (int step = 256; step; step >>= 1)
                if (s_pfx[g + step] <= idx) g += step;
            r_c = blockmajor[(size_t)(g0 + g) * SEGW + s_ml[g] +
                             (idx - s_pfx[g])];
        }
        while (idx < R) {
            const u32 nidx = idx + 512;
            u32 r_n = 0;
            if (nidx < R) {
                u32 g = 0;
                #pragma unroll
                for (int step = 256; step; step >>= 1)
                    if (s_pfx[g + step] <= nidx) g += step;
                r_n = blockmajor[(size_t)(g0 + g) * SEGW + s_ml[g] +
                                 (nidx - s_pfx[g])];   // prefetch next
            }
            const uint4 pc = pal4[r_c & 1023u];        // one palette load
            const u32 local = (r_c >> 10) & (BKTPX - 1);
            atomicAdd(&tileA[local], (u64)pc.x | ((u64)pc.y << 32));
            atomicAdd(&tileB[local], (u64)pc.z | ((u64)pc.w << 32));
            idx = nidx; r_c = r_n;
        }
    }
    __syncthreads();

    uint4* dst = (uint4*)part_ptr(partA, partB, (u32)w);
    for (int t = tid; t < BKTPX; t += 512)
        dst[t] = make_uint4((u32)tileA[t], (u32)(tileA[t] >> 32),
                            (u32)tileB[t], (u32)(tileB[t] >> 32));
}

// ---------------------------------------------------------------------------
// K5: sum partial tiles per bucket, unpack, add raw_image, write CHW out.
// ---------------------------------------------------------------------------
__global__ __launch_bounds__(256) void k_final(
    const u32* __restrict__ partA, const u32* __restrict__ partB,
    const u32* __restrict__ wstart,
    const float* __restrict__ raw, float* __restrict__ out)
{
    const int p = blockIdx.x * 256 + threadIdx.x;
    const int b = p >> 11, local = p & (BKTPX - 1);
    u32 a0 = 0, a1 = 0, a2 = 0, a3 = 0;
    const u32 w0 = wstart[b], w1 = wstart[b + 1];
    for (u32 w = w0; w < w1; ++w) {
        const uint4 v = ((const uint4*)part_ptr_c(partA, partB, w))[local];
        a0 += v.x; a1 += v.y; a2 += v.z; a3 += v.w;
    }
    out[0*(size_t)HW + p] = __fadd_rn(raw[0*(size_t)HW + p], __fmul_rn((float)a0, FPINV));
    out[1*(size_t)HW + p] = __fadd_rn(raw[1*(size_t)HW + p], __fmul_rn((float)a1, FPINV));
    out[2*(size_t)HW + p] = __fadd_rn(raw[2*(size_t)HW + p], __fmul_rn((float)a2, FPINV));
    out[3*(size_t)HW + p] = __fadd_rn(raw[3*(size_t)HW + p], __fmul_rn((float)a3, FPINV));
}

// ---------------------------------------------------------------------------
// Fallback (ws too small): packed u64 global atomics (round-3 path).
// ---------------------------------------------------------------------------
__global__ __launch_bounds__(256) void flame_accum_packed(
    const float* __restrict__ palette,
    const float* __restrict__ Amat, const float* __restrict__ bvec,
    const float* __restrict__ fcolor,
    const float* __restrict__ xy0, const float* __restrict__ c0,
    const float* __restrict__ minv, const float* __restrict__ rangev,
    const int* __restrict__ fn_idx, const int* __restrict__ skipk_ptr,
    u64* __restrict__ ws)
{
    __shared__ __align__(16) float s_pal[FID * 4];
    __shared__ float s_tab[NF * 8];
    for (int t = threadIdx.x; t < FID; t += 256)
        ((float4*)s_pal)[t] = ((const float4*)palette)[t];
    LOAD_TABLES();
    __syncthreads();

    const int i = blockIdx.x * 256 + threadIdx.x;
    if (i >= NPTS) return;
    const int   skipk = skipk_ptr[0];
    const float minx = minv[0], miny = minv[1];
    const float rx = rangev[0], ry = rangev[1];
    const float2 xyv = ((const float2*)xy0)[i];
    float x = xyv.x, y = xyv.y, c = c0[i];
    for (int k = 0; k < KSTEPS; ++k) {
        const int idx = fn_idx[(size_t)k * NPTS + i];
        int xb, yb; bool inb;
        FLAME_STEP(idx, k);
        if (inb) {
            int pi = (int)__fadd_rn(__fmul_rn(c, 999.0f), 0.0005f);
            pi = min(max(pi, 0), FID - 1);
            const float4 col = *(const float4*)&s_pal[pi * 4];
            const u32 u0 = __float2uint_rn(__fmul_rn(col.x, FPSCALE));
            const u32 u1 = __float2uint_rn(__fmul_rn(col.y, FPSCALE));
            const u32 u2 = __float2uint_rn(__fmul_rn(col.z, FPSCALE));
            const u32 u3 = __float2uint_rn(__fmul_rn(col.w, FPSCALE));
            u64* p = ws + ((size_t)xb * IMG_W + yb) * 2;
            atomicAdd(p + 0, (u64)u0 | ((u64)u1 << 32));
            atomicAdd(p + 1, (u64)u2 | ((u64)u3 << 32));
        }
    }
}

__global__ __launch_bounds__(256) void reduce_packed(
    const u64* __restrict__ ws, const float* __restrict__ raw_image,
    float* __restrict__ out)
{
    const int p = blockIdx.x * 256 + threadIdx.x;
    if (p >= HW) return;
    const u64 w0 = ws[(size_t)p * 2 + 0];
    const u64 w1 = ws[(size_t)p * 2 + 1];
    out[0*(size_t)HW+p] = raw_image[0*(size_t)HW+p] + (float)(u32)(w0 & 0xffffffffull) * FPINV;
    out[1*(size_t)HW+p] = raw_image[1*(size_t)HW+p] + (float)(u32)(w0 >> 32)           * FPINV;
    out[2*(size_t)HW+p] = raw_image[2*(size_t)HW+p] + (float)(u32)(w1 & 0xffffffffull) * FPINV;
    out[3*(size_t)HW+p] = raw_image[3*(size_t)HW+p] + (float)(u32)(w1 >> 32)           * FPINV;
}

extern "C" void kernel_launch(void* const* d_in, const int* in_sizes, int n_in,
                              void* d_out, int out_size, void* d_ws, size_t ws_size,
                              hipStream_t stream) {
    const float* raw_image = (const float*)d_in[0];
    const float* palette   = (const float*)d_in[1];
    const float* A         = (const float*)d_in[2];
    const float* b         = (const float*)d_in[3];
    const float* fcolor    = (const float*)d_in[4];
    const float* xy0       = (const float*)d_in[5];
    const float* c0        = (const float*)d_in[6];
    const float* minv      = (const float*)d_in[7];
    const float* rangev    = (const float*)d_in[8];
    const int*   fn_idx    = (const int*)d_in[9];
    const int*   skipk     = (const int*)d_in[10];
    float* img = (float*)d_out;

    // ws layout (u32 units). counts+lpre (16 MB) are dead after k_transpose,
    // so the first PARTA_CH partial tiles alias them (partA); the remaining
    // tiles live in partB after blockmajor.
    u32* ws = (u32*)d_ws;
    const size_t NBG = (size_t)NB * NBKT;                  // 2,000,384
    u32* counts     = ws;                                  // NBG
    u32* lpre       = counts + NBG;                        // NBG
    u32* counts_t   = lpre + NBG;                          // NBG
    u32* lpre_t     = counts_t + NBG;                      // NBG
    u32* totals     = lpre_t + NBG;                        // 512
    u32* mm         = totals + NBKT;                       // 512
    u32* wstart     = mm + NBKT;                           // 513 (pad 1024)
    u32* pal_u32    = wstart + 1024;                       // 4096
    u32* blockmajor = pal_u32 + 4096;                      // NB*SEGW (128MB)
    u32* partB      = blockmajor + (size_t)NB * SEGW;      // (PARTCH-488)*8192
    u32* partA      = counts;                              // aliased
    const size_t need_u32 = (size_t)(partB - ws) +
                            (size_t)(PARTCH - PARTA_CH) * (BKTPX * 4);
    const size_t NEED = need_u32 * sizeof(u32);            // ~177.36 MB

    if (ws_size >= NEED) {
        hipMemsetAsync(totals, 0, NBKT * sizeof(u32), stream);
        k_flame<<<dim3(NB), 256, 0, stream>>>(A, b, fcolor, xy0, c0, minv,
                                              rangev, fn_idx, skipk,
                                              counts, lpre, blockmajor);
        k_transpose<<<dim3(NBKT / TT, (NB + TT - 1) / TT), 256, 0, stream>>>(
            counts, lpre, counts_t, lpre_t, totals);
        k_meta<<<dim3(1), 512, 0, stream>>>(palette, totals, mm, wstart,
                                            pal_u32);
        k_accum<<<dim3(K5G), 512, 0, stream>>>(pal_u32, counts_t, lpre_t, mm,
                                               wstart, blockmajor,
                                               partA, partB);
        k_final<<<dim3(HW / 256), 256, 0, stream>>>(partA, partB, wstart,
                                                    raw_image, img);
    } else {
        const size_t need2 = (size_t)HW * 2 * sizeof(u64);
        hipMemsetAsync(d_ws, 0, need2, stream);
        flame_accum_packed<<<dim3(NB), 256, 0, stream>>>(
            palette, A, b, fcolor, xy0, c0, minv, rangev, fn_idx, skipk,
            (u64*)d_ws);
        reduce_packed<<<dim3((HW + 255) / 256), 256, 0, stream>>>(
            (const u64*)d_ws, raw_image, img);
    }
}

// Round 23
// 163.007 us; speedup vs baseline: 1.0409x; 1.0409x over previous
//
#include <hip/hip_runtime.h>

typedef unsigned int u32;
typedef unsigned long long u64;

#define NPTS   1000000
#define KSTEPS 32
#define NF     8
#define IMG_H  1024
#define IMG_W  1024
#define FID    1000
#define HW     (IMG_H * IMG_W)
#define NB     3907            // ceil(NPTS/256)
#define NBKT   512             // bucket = pixel >> 11  (2 image rows)
#define BKTPX  2048            // pixels per bucket
#define SEGW   (256 * KSTEPS)  // 8192 words per block-major segment
#define K5G    1024            // accumulate grid (>= PARTCH)
#define PARTCH 1016            // max chunks = 512 + 504
#define PARTA_CH 488           // chunk tiles aliased over counts+lpre region
#define MSTG   512             // meta staging span (g's per stage)
#define TT     64              // transpose tile
#define FPSCALE 4194304.0f     // 2^22 fixed point; capacity 1024 > max sum 488
#define FPINV   (1.0f / 4194304.0f)

// Extract step K's function index from packed nibble words p0..p3.
#define GETIDX(K)                                                              \
    ((int)(((((K) >> 3) == 0 ? p0 : ((K) >> 3) == 1 ? p1                       \
            : ((K) >> 3) == 2 ? p2 : p3) >> (((K) & 7) * 4)) & 7u))

// One chaos-game step, numpy-exact (no FMA contraction). Scalar LDS table
// reads: 8 distinct rows max -> broadcast/2-way aliasing (free on CDNA4).
#define FLAME_STEP(IDX, K)                                                     \
  {                                                                            \
    const float a00 = s_tab[(IDX)*8+0], a01 = s_tab[(IDX)*8+1];                \
    const float a10 = s_tab[(IDX)*8+2], a11 = s_tab[(IDX)*8+3];                \
    const float b0  = s_tab[(IDX)*8+4], b1  = s_tab[(IDX)*8+5];                \
    const float fc  = s_tab[(IDX)*8+6];                                        \
    const float nx = __fadd_rn(__fadd_rn(__fmul_rn(a00,x),__fmul_rn(a01,y)),b0);\
    const float ny = __fadd_rn(__fadd_rn(__fmul_rn(a10,x),__fmul_rn(a11,y)),b1);\
    x = nx; y = ny;                                                            \
    c = __fmul_rn(__fadd_rn(c, fc), 0.5f);                                     \
    xb = (int)__fmul_rn(__fsub_rn(x, minx), rx);                               \
    yb = (int)__fmul_rn(__fsub_rn(y, miny), ry);                               \
    inb = (xb >= 0) & (xb < IMG_W) & (yb >= 0) & (yb < IMG_H) & ((K) >= skipk);\
  }

#define LOAD_TABLES()                                                          \
    if (threadIdx.x < NF) {                                                    \
        const int f = threadIdx.x;                                             \
        s_tab[f*8+0] = Amat[f*4+0]; s_tab[f*8+1] = Amat[f*4+1];                \
        s_tab[f*8+2] = Amat[f*4+2]; s_tab[f*8+3] = Amat[f*4+3];                \
        s_tab[f*8+4] = bvec[f*2+0]; s_tab[f*8+5] = bvec[f*2+1];                \
        s_tab[f*8+6] = fcolor[f];   s_tab[f*8+7] = 0.0f;                       \
    }

__device__ __forceinline__ u32* part_ptr(u32* partA, u32* partB, u32 w) {
    return (w < PARTA_CH) ? partA + (size_t)w * (BKTPX * 4)
                          : partB + (size_t)(w - PARTA_CH) * (BKTPX * 4);
}
__device__ __forceinline__ const u32* part_ptr_c(const u32* partA,
                                                 const u32* partB, u32 w) {
    return (w < PARTA_CH) ? partA + (size_t)w * (BKTPX * 4)
                          : partB + (size_t)(w - PARTA_CH) * (BKTPX * 4);
}

// Wave-level inclusive scan of v across the 64-lane wave (6 shfl steps).
__device__ __forceinline__ u32 wave_incl_scan(u32 v, int lane) {
    #pragma unroll
    for (int o = 1; o < 64; o <<= 1) {
        const u32 n = __shfl_up(v, o);
        if (lane >= o) v += n;
    }
    return v;
}

// ---------------------------------------------------------------------------
// K1: the ONLY flame pass (round-21 champion, byte-identical).
// ---------------------------------------------------------------------------
__global__ __launch_bounds__(256) void k_flame(
    const float* __restrict__ Amat, const float* __restrict__ bvec,
    const float* __restrict__ fcolor,
    const float* __restrict__ xy0, const float* __restrict__ c0,
    const float* __restrict__ minv, const float* __restrict__ rangev,
    const int* __restrict__ fn_idx, const int* __restrict__ skipk_ptr,
    u32* __restrict__ counts, u32* __restrict__ lpre,
    u32* __restrict__ blockmajor)
{
    __shared__ u32 s_rec[SEGW];          // 32 KB
    __shared__ u32 s_cnt[NBKT];          // counts, then cursors
    __shared__ u32 s_wsum[4];
    __shared__ u32 s_vt;
    __shared__ float s_tab[NF * 8];
    const int tid = threadIdx.x;
    const int lane = tid & 63, wav = tid >> 6;

    s_cnt[tid] = 0u; s_cnt[tid + 256] = 0u;
    LOAD_TABLES();
    __syncthreads();

    const int i = blockIdx.x * 256 + tid;
    u32 rec[KSTEPS];

    if (i < NPTS) {
        u32 p0 = 0, p1 = 0, p2 = 0, p3 = 0;
        #pragma unroll
        for (int k = 0; k < 8; ++k)
            p0 |= ((u32)fn_idx[(size_t)k * NPTS + i] & 7u) << (k * 4);
        #pragma unroll
        for (int k = 0; k < 8; ++k)
            p1 |= ((u32)fn_idx[(size_t)(k + 8) * NPTS + i] & 7u) << (k * 4);
        #pragma unroll
        for (int k = 0; k < 8; ++k)
            p2 |= ((u32)fn_idx[(size_t)(k + 16) * NPTS + i] & 7u) << (k * 4);
        #pragma unroll
        for (int k = 0; k < 8; ++k)
            p3 |= ((u32)fn_idx[(size_t)(k + 24) * NPTS + i] & 7u) << (k * 4);

        const int   skipk = skipk_ptr[0];
        const float minx = minv[0], miny = minv[1];
        const float rx = rangev[0], ry = rangev[1];
        const float2 xyv = ((const float2*)xy0)[i];
        float x = xyv.x, y = xyv.y, c = c0[i];
        #pragma unroll
        for (int k = 0; k < KSTEPS; ++k) {
            const int idx = GETIDX(k);
            int xb, yb; bool inb;
            FLAME_STEP(idx, k);
            u32 r = 0xFFFFFFFFu;
            if (inb) {
                int pi = (int)__fadd_rn(__fmul_rn(c, 999.0f), 0.0005f);
                pi = min(max(pi, 0), FID - 1);
                r = (((u32)(xb << 10 | yb)) << 10) | (u32)pi;
                atomicAdd(&s_cnt[r >> 21], 1u);
            }
            rec[k] = r;
        }
    }
    __syncthreads();

    // Shuffle-based exclusive scan over 512 bucket counts (2 per thread).
    const u32 cA = s_cnt[2 * tid], cB = s_cnt[2 * tid + 1];
    const u32 psum = cA + cB;
    u32 v = wave_incl_scan(psum, lane);
    if (lane == 63) s_wsum[wav] = v;
    __syncthreads();
    u32 off = 0;
    #pragma unroll
    for (int wv = 0; wv < 4; ++wv)
        if (wv < wav) off += s_wsum[wv];
    const u32 incl = v + off;
    const u32 excl = incl - psum;

    // Cursors in LDS; per-(block,bucket) meta to global (coalesced).
    s_cnt[2 * tid] = excl; s_cnt[2 * tid + 1] = excl + cA;
    const size_t g0 = (size_t)blockIdx.x * NBKT;
    lpre[g0 + 2 * tid] = excl;  lpre[g0 + 2 * tid + 1] = excl + cA;
    counts[g0 + 2 * tid] = cA;  counts[g0 + 2 * tid + 1] = cB;
    if (tid == 255) s_vt = incl;         // total valid records
    __syncthreads();

    // Re-scatter rec[] from VGPRs into LDS, bucket-sorted.
    if (i < NPTS) {
        #pragma unroll
        for (int k = 0; k < KSTEPS; ++k) {
            const u32 r = rec[k];
            if (r != 0xFFFFFFFFu) {
                const u32 pos = atomicAdd(&s_cnt[r >> 21], 1u);
                s_rec[pos] = r;
            }
        }
    }
    __syncthreads();

    // Dense copy to block-major segment (uint4).
    const u32 vt = s_vt;
    u32* dst = blockmajor + (size_t)blockIdx.x * SEGW;
    const u32 nv4 = vt >> 2;
    for (u32 q = tid; q < nv4; q += 256)
        ((uint4*)dst)[q] = make_uint4(s_rec[4*q], s_rec[4*q+1],
                                      s_rec[4*q+2], s_rec[4*q+3]);
    for (u32 j = (nv4 << 2) + tid; j < vt; j += 256) dst[j] = s_rec[j];
}

// ---------------------------------------------------------------------------
// K2: LDS-tiled transpose (64x64, +1-pad) — coalesced both sides. Totals via
// per-block partial sums + one atomic wave (totals pre-zeroed).
// ---------------------------------------------------------------------------
__global__ __launch_bounds__(256) void k_transpose(
    const u32* __restrict__ counts, const u32* __restrict__ lpre,
    u32* __restrict__ counts_t, u32* __restrict__ lpre_t,
    u32* __restrict__ totals)
{
    __shared__ u32 tc[TT][TT + 1];
    __shared__ u32 tl[TT][TT + 1];
    __shared__ u32 psum[4][TT];
    const int tx = threadIdx.x & 63, ty = threadIdx.x >> 6;
    const int b0 = blockIdx.x * TT;      // bucket tile (NBKT/TT = 8)
    const int g0 = blockIdx.y * TT;      // block-row tile (ceil(NB/TT) = 62)

    u32 colsum = 0;
    #pragma unroll
    for (int j = 0; j < 16; ++j) {
        const int g = g0 + ty * 16 + j;
        u32 cv = 0, lv = 0;
        if (g < NB) {
            cv = counts[(size_t)g * NBKT + b0 + tx];   // coalesced
            lv = lpre[(size_t)g * NBKT + b0 + tx];     // coalesced
        }
        tc[ty * 16 + j][tx] = cv;
        tl[ty * 16 + j][tx] = lv;
        colsum += cv;
    }
    psum[ty][tx] = colsum;
    __syncthreads();

    if (ty == 0) {
        const u32 s = psum[0][tx] + psum[1][tx] + psum[2][tx] + psum[3][tx];
        if (s) atomicAdd(&totals[b0 + tx], s);
    }

    #pragma unroll
    for (int j = 0; j < 16; ++j) {
        const int b = b0 + ty * 16 + j;
        const int g = g0 + tx;
        if (g < NB) {
            counts_t[(size_t)b * NB + g] = tc[tx][ty * 16 + j];  // coalesced
            lpre_t[(size_t)b * NB + g]   = tl[tx][ty * 16 + j];  // coalesced
        }
    }
}

// ---------------------------------------------------------------------------
// K3: chunk counts m[b], wstart scan, fixed-point palette. 1 wg x 512.
// ---------------------------------------------------------------------------
__global__ __launch_bounds__(512) void k_meta(
    const float* __restrict__ palette,
    const u32* __restrict__ totals,
    u32* __restrict__ mm, u32* __restrict__ wstart,
    u32* __restrict__ pal_u32)
{
    __shared__ u32 sc[NBKT];
    const int tid = threadIdx.x;

    for (int t = tid; t < FID * 4; t += 512)
        pal_u32[t] = __float2uint_rn(__fmul_rn(palette[t], FPSCALE));

    const u32 t0 = totals[tid];
    sc[tid] = t0; __syncthreads();
    #pragma unroll
    for (int o = 1; o < NBKT; o <<= 1) {
        u32 v = (tid >= o) ? sc[tid - o] : 0u;
        __syncthreads(); sc[tid] += v; __syncthreads();
    }
    const u32 total = sc[NBKT - 1];

    const u32 m = 1u + (total ? (u32)((504ull * t0) / total) : 0u);
    mm[tid] = m;
    __syncthreads(); sc[tid] = m; __syncthreads();
    #pragma unroll
    for (int o = 1; o < NBKT; o <<= 1) {
        u32 v = (tid >= o) ? sc[tid - o] : 0u;
        __syncthreads(); sc[tid] += v; __syncthreads();
    }
    wstart[tid] = sc[tid] - m;
    if (tid == NBKT - 1) wstart[NBKT] = sc[NBKT - 1];
}

// ---------------------------------------------------------------------------
// K4 v10: round-16 v6 walk + shuffle scan (round-21 champion).
// ---------------------------------------------------------------------------
__global__ __launch_bounds__(512) void k_accum(
    const u32* __restrict__ pal_u32,
    const u32* __restrict__ counts_t, const u32* __restrict__ lpre_t,
    const u32* __restrict__ mm, const u32* __restrict__ wstart,
    const u32* __restrict__ blockmajor,
    u32* __restrict__ partA, u32* __restrict__ partB)
{
    __shared__ u64 tileA[BKTPX];        // ch0|ch1 (16 KB)
    __shared__ u64 tileB[BKTPX];        // ch2|ch3 (16 KB)
    __shared__ u32 s_ml[MSTG];          // staged lp (2 KB)
    __shared__ u32 s_pfx[MSTG + 1];     // run starts
    __shared__ u32 s_ws[NBKT + 1];
    __shared__ u32 s_wsum[8];
    const int tid = threadIdx.x, w = blockIdx.x;
    const int lane = tid & 63, wav = tid >> 6;

    if (tid < NBKT) s_ws[tid] = wstart[tid];
    if (tid == 0)   s_ws[NBKT] = wstart[NBKT];
    __syncthreads();
    if ((u32)w >= s_ws[NBKT]) return;   // uniform per block

    int b = 0;
    #pragma unroll
    for (int step = 256; step; step >>= 1)
        if (b + step <= NBKT - 1 && s_ws[b + step] <= (u32)w) b += step;

    for (int t = tid; t < BKTPX; t += 512) { tileA[t] = 0ull; tileB[t] = 0ull; }

    const u32 m = mm[b], cch = (u32)w - s_ws[b];
    const u32 gs = (u32)(((u64)NB * cch) / m);
    const u32 ge = (u32)(((u64)NB * (cch + 1)) / m);

    const uint4* pal4 = (const uint4*)pal_u32;
    const u32* ct = counts_t + (size_t)b * NB;
    const u32* lt = lpre_t + (size_t)b * NB;

    for (u32 g0 = gs; g0 < ge; g0 += MSTG) {
        const u32 nm = min((u32)MSTG, ge - g0);
        __syncthreads();                 // protect prior stage's readers
        const u32 myc = (tid < (int)nm) ? ct[g0 + tid] : 0u;   // coalesced
        if (tid < (int)nm) s_ml[tid] = lt[g0 + tid];           // coalesced

        // Shuffle-based inclusive scan of myc over 512 threads (2 barriers).
        u32 v = wave_incl_scan(myc, lane);
        if (lane == 63) s_wsum[wav] = v;
        __syncthreads();
        u32 off = 0;
        #pragma unroll
        for (int wv = 0; wv < 8; ++wv)
            if (wv < wav) off += s_wsum[wv];
        s_pfx[tid + 1] = v + off;        // inclusive
        if (tid == 0) s_pfx[0] = 0u;
        __syncthreads();
        const u32 R = s_pfx[MSTG];       // records in this stage

        // Flat, balanced walk with one-ahead pipeline (v6 structure).
        u32 idx = (u32)tid;
        u32 r_c = 0;
        if (idx < R) {
            u32 g = 0;
            #pragma unroll
            for (int step = 256; step; step >>= 1)
                if (s_pfx[g + step] <= idx) g += step;
            r_c = blockmajor[(size_t)(g0 + g) * SEGW + s_ml[g] +
                             (idx - s_pfx[g])];
        }
        while (idx < R) {
            const u32 nidx = idx + 512;
            u32 r_n = 0;
            if (nidx < R) {
                u32 g = 0;
                #pragma unroll
                for (int step = 256; step; step >>= 1)
                    if (s_pfx[g + step] <= nidx) g += step;
                r_n = blockmajor[(size_t)(g0 + g) * SEGW + s_ml[g] +
                                 (nidx - s_pfx[g])];   // prefetch next
            }
            const uint4 pc = pal4[r_c & 1023u];        // one palette load
            const u32 local = (r_c >> 10) & (BKTPX - 1);
            atomicAdd(&tileA[local], (u64)pc.x | ((u64)pc.y << 32));
            atomicAdd(&tileB[local], (u64)pc.z | ((u64)pc.w << 32));
            idx = nidx; r_c = r_n;
        }
    }
    __syncthreads();

    uint4* dst = (uint4*)part_ptr(partA, partB, (u32)w);
    for (int t = tid; t < BKTPX; t += 512)
        dst[t] = make_uint4((u32)tileA[t], (u32)(tileA[t] >> 32),
                            (u32)tileB[t], (u32)(tileB[t] >> 32));
}

// ---------------------------------------------------------------------------
// K5: sum partial tiles per bucket, unpack, add raw_image, write CHW out.
// ---------------------------------------------------------------------------
__global__ __launch_bounds__(256) void k_final(
    const u32* __restrict__ partA, const u32* __restrict__ partB,
    const u32* __restrict__ wstart,
    const float* __restrict__ raw, float* __restrict__ out)
{
    const int p = blockIdx.x * 256 + threadIdx.x;
    const int b = p >> 11, local = p & (BKTPX - 1);
    u32 a0 = 0, a1 = 0, a2 = 0, a3 = 0;
    const u32 w0 = wstart[b], w1 = wstart[b + 1];
    for (u32 w = w0; w < w1; ++w) {
        const uint4 v = ((const uint4*)part_ptr_c(partA, partB, w))[local];
        a0 += v.x; a1 += v.y; a2 += v.z; a3 += v.w;
    }
    out[0*(size_t)HW + p] = __fadd_rn(raw[0*(size_t)HW + p], __fmul_rn((float)a0, FPINV));
    out[1*(size_t)HW + p] = __fadd_rn(raw[1*(size_t)HW + p], __fmul_rn((float)a1, FPINV));
    out[2*(size_t)HW + p] = __fadd_rn(raw[2*(size_t)HW + p], __fmul_rn((float)a2, FPINV));
    out[3*(size_t)HW + p] = __fadd_rn(raw[3*(size_t)HW + p], __fmul_rn((float)a3, FPINV));
}

// ---------------------------------------------------------------------------
// Fallback (ws too small): packed u64 global atomics (round-3 path).
// ---------------------------------------------------------------------------
__global__ __launch_bounds__(256) void flame_accum_packed(
    const float* __restrict__ palette,
    const float* __restrict__ Amat, const float* __restrict__ bvec,
    const float* __restrict__ fcolor,
    const float* __restrict__ xy0, const float* __restrict__ c0,
    const float* __restrict__ minv, const float* __restrict__ rangev,
    const int* __restrict__ fn_idx, const int* __restrict__ skipk_ptr,
    u64* __restrict__ ws)
{
    __shared__ __align__(16) float s_pal[FID * 4];
    __shared__ float s_tab[NF * 8];
    for (int t = threadIdx.x; t < FID; t += 256)
        ((float4*)s_pal)[t] = ((const float4*)palette)[t];
    LOAD_TABLES();
    __syncthreads();

    const int i = blockIdx.x * 256 + threadIdx.x;
    if (i >= NPTS) return;
    const int   skipk = skipk_ptr[0];
    const float minx = minv[0], miny = minv[1];
    const float rx = rangev[0], ry = rangev[1];
    const float2 xyv = ((const float2*)xy0)[i];
    float x = xyv.x, y = xyv.y, c = c0[i];
    for (int k = 0; k < KSTEPS; ++k) {
        const int idx = fn_idx[(size_t)k * NPTS + i];
        int xb, yb; bool inb;
        FLAME_STEP(idx, k);
        if (inb) {
            int pi = (int)__fadd_rn(__fmul_rn(c, 999.0f), 0.0005f);
            pi = min(max(pi, 0), FID - 1);
            const float4 col = *(const float4*)&s_pal[pi * 4];
            const u32 u0 = __float2uint_rn(__fmul_rn(col.x, FPSCALE));
            const u32 u1 = __float2uint_rn(__fmul_rn(col.y, FPSCALE));
            const u32 u2 = __float2uint_rn(__fmul_rn(col.z, FPSCALE));
            const u32 u3 = __float2uint_rn(__fmul_rn(col.w, FPSCALE));
            u64* p = ws + ((size_t)xb * IMG_W + yb) * 2;
            atomicAdd(p + 0, (u64)u0 | ((u64)u1 << 32));
            atomicAdd(p + 1, (u64)u2 | ((u64)u3 << 32));
        }
    }
}

__global__ __launch_bounds__(256) void reduce_packed(
    const u64* __restrict__ ws, const float* __restrict__ raw_image,
    float* __restrict__ out)
{
    const int p = blockIdx.x * 256 + threadIdx.x;
    if (p >= HW) return;
    const u64 w0 = ws[(size_t)p * 2 + 0];
    const u64 w1 = ws[(size_t)p * 2 + 1];
    out[0*(size_t)HW+p] = raw_image[0*(size_t)HW+p] + (float)(u32)(w0 & 0xffffffffull) * FPINV;
    out[1*(size_t)HW+p] = raw_image[1*(size_t)HW+p] + (float)(u32)(w0 >> 32)           * FPINV;
    out[2*(size_t)HW+p] = raw_image[2*(size_t)HW+p] + (float)(u32)(w1 & 0xffffffffull) * FPINV;
    out[3*(size_t)HW+p] = raw_image[3*(size_t)HW+p] + (float)(u32)(w1 >> 32)           * FPINV;
}

extern "C" void kernel_launch(void* const* d_in, const int* in_sizes, int n_in,
                              void* d_out, int out_size, void* d_ws, size_t ws_size,
                              hipStream_t stream) {
    const float* raw_image = (const float*)d_in[0];
    const float* palette   = (const float*)d_in[1];
    const float* A         = (const float*)d_in[2];
    const float* b         = (const float*)d_in[3];
    const float* fcolor    = (const float*)d_in[4];
    const float* xy0       = (const float*)d_in[5];
    const float* c0        = (const float*)d_in[6];
    const float* minv      = (const float*)d_in[7];
    const float* rangev    = (const float*)d_in[8];
    const int*   fn_idx    = (const int*)d_in[9];
    const int*   skipk     = (const int*)d_in[10];
    float* img = (float*)d_out;

    // ws layout (u32 units). counts+lpre (16 MB) are dead after k_transpose,
    // so the first PARTA_CH partial tiles alias them (partA); the remaining
    // tiles live in partB after blockmajor.
    u32* ws = (u32*)d_ws;
    const size_t NBG = (size_t)NB * NBKT;                  // 2,000,384
    u32* counts     = ws;                                  // NBG
    u32* lpre       = counts + NBG;                        // NBG
    u32* counts_t   = lpre + NBG;                          // NBG
    u32* lpre_t     = counts_t + NBG;                      // NBG
    u32* totals     = lpre_t + NBG;                        // 512
    u32* mm         = totals + NBKT;                       // 512
    u32* wstart     = mm + NBKT;                           // 513 (pad 1024)
    u32* pal_u32    = wstart + 1024;                       // 4096
    u32* blockmajor = pal_u32 + 4096;                      // NB*SEGW (128MB)
    u32* partB      = blockmajor + (size_t)NB * SEGW;      // (PARTCH-488)*8192
    u32* partA      = counts;                              // aliased
    const size_t need_u32 = (size_t)(partB - ws) +
                            (size_t)(PARTCH - PARTA_CH) * (BKTPX * 4);
    const size_t NEED = need_u32 * sizeof(u32);            // ~177.36 MB

    if (ws_size >= NEED) {
        hipMemsetAsync(totals, 0, NBKT * sizeof(u32), stream);
        k_flame<<<dim3(NB), 256, 0, stream>>>(A, b, fcolor, xy0, c0, minv,
                                              rangev, fn_idx, skipk,
                                              counts, lpre, blockmajor);
        k_transpose<<<dim3(NBKT / TT, (NB + TT - 1) / TT), 256, 0, stream>>>(
            counts, lpre, counts_t, lpre_t, totals);
        k_meta<<<dim3(1), 512, 0, stream>>>(palette, totals, mm, wstart,
                                            pal_u32);
        k_accum<<<dim3(K5G), 512, 0, stream>>>(pal_u32, counts_t, lpre_t, mm,
                                               wstart, blockmajor,
                                               partA, partB);
        k_final<<<dim3(HW / 256), 256, 0, stream>>>(partA, partB, wstart,
                                                    raw_image, img);
    } else {
        const size_t need2 = (size_t)HW * 2 * sizeof(u64);
        hipMemsetAsync(d_ws, 0, need2, stream);
        flame_accum_packed<<<dim3(NB), 256, 0, stream>>>(
            palette, A, b, fcolor, xy0, c0, minv, rangev, fn_idx, skipk,
            (u64*)d_ws);
        reduce_packed<<<dim3((HW + 255) / 256), 256, 0, stream>>>(
            (const u64*)d_ws, raw_image, img);
    }
}